// Round 1
// 94.131 us; speedup vs baseline: 1.0101x; 1.0101x over previous
//
#include <hip/hip_runtime.h>
#include <math.h>

#define D      3
#define HID    64
#define WIDTH  64
#define BATCH  500000
#define BLOCKP (D * WIDTH)          // 192
#define NPAR   (3 * BLOCKP + WIDTH) // 640
#define NPAIR  (BATCH / 2)          // 250000 pairs of 2 elements

typedef float f2 __attribute__((ext_vector_type(2)));

__device__ __forceinline__ f2 sp(float s) { f2 r; r.x = s; r.y = s; return r; }
__device__ __forceinline__ f2 vfma(f2 a, f2 b, f2 c) {
    return __builtin_elementwise_fma(a, b, c);
}

// ---------------- kernel 1: hypernet (single block) ----------------
// Computes the folded parameter table once and writes 128 float4 (2 KB)
// to the workspace: par[0..63] = {W0*c, W1*c, W2*c, B*c},
//                   par[64..127] = {U0/64, U1/64, U2/64, -wu/64}.
__global__ __launch_bounds__(256) void hyper_kernel(
    const float* __restrict__ t,
    const float* __restrict__ fc1_w, const float* __restrict__ fc1_b,
    const float* __restrict__ fc2_w, const float* __restrict__ fc2_b,
    const float* __restrict__ fc3_w, const float* __restrict__ fc3_b,
    float4* __restrict__ par)
{
    __shared__ float p1[HID];
    __shared__ float p2[HID];
    __shared__ float p3[NPAR];

    const int tid = threadIdx.x;

    if (tid < HID) {
        p1[tid] = tanhf(t[0] * fc1_w[tid] + fc1_b[tid]);
    }
    __syncthreads();
    if (tid < HID) {
        const float* wrow = fc2_w + tid * HID;
        float a0 = 0.f, a1 = 0.f, a2 = 0.f, a3 = 0.f;
        #pragma unroll
        for (int k = 0; k < HID; k += 4) {
            a0 = fmaf(wrow[k + 0], p1[k + 0], a0);
            a1 = fmaf(wrow[k + 1], p1[k + 1], a1);
            a2 = fmaf(wrow[k + 2], p1[k + 2], a2);
            a3 = fmaf(wrow[k + 3], p1[k + 3], a3);
        }
        p2[tid] = tanhf(((a0 + a1) + (a2 + a3)) + fc2_b[tid]);
    }
    __syncthreads();
    for (int o = tid; o < NPAR; o += blockDim.x) {
        float acc = fc3_b[o];
        const float4* w4 = (const float4*)(fc3_w + o * HID);
        const float4* q4 = (const float4*)p2;
        #pragma unroll
        for (int k = 0; k < HID / 4; ++k) {
            float4 w = w4[k];
            float4 q = q4[k];
            acc += w.x * q.x + w.y * q.y + w.z * q.z + w.w * q.w;
        }
        p3[o] = acc;
    }
    __syncthreads();
    if (tid < WIDTH) {
        float W0 = p3[3 * tid + 0], W1 = p3[3 * tid + 1], W2 = p3[3 * tid + 2];
        float U0 = p3[BLOCKP + 3 * tid + 0], U1 = p3[BLOCKP + 3 * tid + 1], U2 = p3[BLOCKP + 3 * tid + 2];
        float G0 = p3[2 * BLOCKP + 3 * tid + 0], G1 = p3[2 * BLOCKP + 3 * tid + 1], G2 = p3[2 * BLOCKP + 3 * tid + 2];
        float B  = p3[3 * BLOCKP + tid];
        U0 *= 1.0f / (1.0f + expf(-G0));
        U1 *= 1.0f / (1.0f + expf(-G1));
        U2 *= 1.0f / (1.0f + expf(-G2));
        float wu = W0 * U0 + W1 * U1 + W2 * U2;   // from UNSCALED W,U
        // fold 2*log2(e) into W,B: tanh(x) = 1 - 2/(1 + 2^(c*x))
        const float c = 2.8853900817779268f;
        const float s = 1.0f / (float)WIDTH;
        par[tid]         = make_float4(W0 * c, W1 * c, W2 * c, B * c);
        par[WIDTH + tid] = make_float4(U0 * s, U1 * s, U2 * s, -wu * s);
    }
}

// ---------------- kernel 2: batch loop, 2 elements/thread ----------------
// No hypernet prologue: 2 KB param table copied global->LDS, then straight
// into the j-loop. 977 blocks -> ~3.8 waves/SIMD (was 1.9) for trans/VALU
// pipe overlap.
__global__ __launch_bounds__(256) void cnf_main(
    const float* __restrict__ z,
    const float4* __restrict__ par,
    float* __restrict__ out)
{
    __shared__ float4 stab[2 * WIDTH];   // [0..63]=pA, [64..127]=pB

    const int tid = threadIdx.x;
    if (tid < 2 * WIDTH) stab[tid] = par[tid];
    __syncthreads();

    const int gid = blockIdx.x * blockDim.x + tid;
    if (gid >= NPAIR) return;

    // elements e0 = 2*gid, e1 = 2*gid+1; z row-major [BATCH][3]
    const f2* zp = (const f2*)z + (size_t)gid * 3;   // 24B/thread, 8B aligned
    f2 v0 = zp[0], v1 = zp[1], v2 = zp[2];
    f2 z0 = {v0.x, v1.y};   // {z[e0][0], z[e1][0]}
    f2 z1 = {v0.y, v2.x};   // {z[e0][1], z[e1][1]}
    f2 z2 = {v1.x, v2.y};   // {z[e0][2], z[e1][2]}

    f2 dz0 = sp(0.f), dz1 = sp(0.f), dz2 = sp(0.f), tr = sp(0.f);

    const float4* sA = stab;
    const float4* sB = stab + WIDTH;

    #pragma unroll 8
    for (int j = 0; j < WIDTH; ++j) {
        float4 a = sA[j];   // scaled W0,W1,W2,B (LDS broadcast, conflict-free)
        float4 b = sB[j];   // scaled U0,U1,U2,-wu

        // x' = c*(z.W + B), clamped at 30 (exact: h(30') == 1.0f in fp32;
        // also keeps the 2-way Montgomery product finite)
        f2 x = vfma(z0, sp(a.x), vfma(z1, sp(a.y), vfma(z2, sp(a.z), sp(a.w))));
        x = __builtin_elementwise_min(x, sp(30.0f));

        f2 d;                                  // d_e = 1 + 2^(x'_e)
        d.x = __builtin_amdgcn_exp2f(x.x);
        d.y = __builtin_amdgcn_exp2f(x.y);
        d = d + sp(1.0f);

        // Montgomery batch inversion over the pair: 1 rcp for 2 elements
        float R = __builtin_amdgcn_rcpf(d.x * d.y);
        f2 inv; inv.x = R * d.y; inv.y = R * d.x;

        f2 h  = vfma(sp(-2.0f), inv, sp(1.0f));  // tanh
        f2 g1 = vfma(-h, h, sp(1.0f));           // 1 - h^2

        dz0 = vfma(h,  sp(b.x), dz0);
        dz1 = vfma(h,  sp(b.y), dz1);
        dz2 = vfma(h,  sp(b.z), dz2);
        tr  = vfma(g1, sp(b.w), tr);
    }

    // scale (1/64) and trace negation pre-folded into pB
    f2* o = (f2*)out + (size_t)gid * 3;
    f2 w0 = {dz0.x, dz1.x};
    f2 w1 = {dz2.x, dz0.y};
    f2 w2 = {dz1.y, dz2.y};
    o[0] = w0; o[1] = w1; o[2] = w2;

    ((f2*)(out + 3 * BATCH))[gid] = tr;          // dlogp pair, coalesced
}

extern "C" void kernel_launch(void* const* d_in, const int* in_sizes, int n_in,
                              void* d_out, int out_size, void* d_ws, size_t ws_size,
                              hipStream_t stream) {
    const float* t     = (const float*)d_in[0];
    const float* z     = (const float*)d_in[1];
    // d_in[2] = logp_z : unused by the reference computation
    const float* fc1_w = (const float*)d_in[3];
    const float* fc1_b = (const float*)d_in[4];
    const float* fc2_w = (const float*)d_in[5];
    const float* fc2_b = (const float*)d_in[6];
    const float* fc3_w = (const float*)d_in[7];
    const float* fc3_b = (const float*)d_in[8];
    float* out = (float*)d_out;

    float4* par = (float4*)d_ws;   // 2 KB param table, written each iteration

    hyper_kernel<<<1, 256, 0, stream>>>(
        t, fc1_w, fc1_b, fc2_w, fc2_b, fc3_w, fc3_b, par);

    const int threads = 256;
    const int blocks  = (NPAIR + threads - 1) / threads;  // 977
    cnf_main<<<blocks, threads, 0, stream>>>(z, par, out);
}

// Round 2
// 92.650 us; speedup vs baseline: 1.0262x; 1.0160x over previous
//
#include <hip/hip_runtime.h>
#include <math.h>

#define D      3
#define HID    64
#define WIDTH  64
#define BATCH  500000
#define BLOCKP (D * WIDTH)          // 192
#define NPAR   (3 * BLOCKP + WIDTH) // 640
#define NPAIR  (BATCH / 2)          // 250000 pairs of 2 elements

typedef float f2 __attribute__((ext_vector_type(2)));

__device__ __forceinline__ f2 sp(float s) { f2 r; r.x = s; r.y = s; return r; }
__device__ __forceinline__ f2 vfma(f2 a, f2 b, f2 c) {
    return __builtin_elementwise_fma(a, b, c);
}

// ---------------- kernel 1: hypernet (64 blocks x 64 threads) ----------------
// Block b computes ONLY the 10 fc3 rows needed for folded output b:
//   rows 3b..3b+2 (W), BLOCKP+3b.. (U), 2*BLOCKP+3b.. (G), 3*BLOCKP+b (B).
// p1/p2 are recomputed redundantly per block (64+4096 FMAs - negligible);
// fc3_w traffic is 2.5 KB/block with zero redundancy, spread over 64 CUs
// instead of 164 KB serially on one CU.
// Writes par[0..63] = {W0*c, W1*c, W2*c, B*c}, par[64..127] = {U0/64, U1/64,
// U2/64, -wu/64}  (c = 2*log2(e), tanh(x) = 1 - 2/(1 + 2^(c*x))).
__global__ __launch_bounds__(64) void hyper_kernel(
    const float* __restrict__ t,
    const float* __restrict__ fc1_w, const float* __restrict__ fc1_b,
    const float* __restrict__ fc2_w, const float* __restrict__ fc2_b,
    const float* __restrict__ fc3_w, const float* __restrict__ fc3_b,
    float4* __restrict__ par)
{
    __shared__ float p1[HID];
    __shared__ float p2[HID];
    __shared__ float q[16];          // 10 used

    const int tid = threadIdx.x;
    const int tb  = blockIdx.x;      // fold output index 0..63

    p1[tid] = tanhf(t[0] * fc1_w[tid] + fc1_b[tid]);
    __syncthreads();
    {
        const float* wrow = fc2_w + tid * HID;
        float a0 = 0.f, a1 = 0.f, a2 = 0.f, a3 = 0.f;
        #pragma unroll
        for (int k = 0; k < HID; k += 4) {
            a0 = fmaf(wrow[k + 0], p1[k + 0], a0);
            a1 = fmaf(wrow[k + 1], p1[k + 1], a1);
            a2 = fmaf(wrow[k + 2], p1[k + 2], a2);
            a3 = fmaf(wrow[k + 3], p1[k + 3], a3);
        }
        p2[tid] = tanhf(((a0 + a1) + (a2 + a3)) + fc2_b[tid]);
    }
    __syncthreads();
    if (tid < 10) {
        // tid 0..2 -> W rows, 3..5 -> U rows, 6..8 -> G rows, 9 -> B row
        const int row = (tid < 9) ? ((tid / 3) * BLOCKP + 3 * tb + (tid % 3))
                                  : (3 * BLOCKP + tb);
        const float4* w4 = (const float4*)(fc3_w + (size_t)row * HID);
        const float4* q4 = (const float4*)p2;
        float acc = fc3_b[row];
        #pragma unroll
        for (int k = 0; k < HID / 4; ++k) {
            float4 w = w4[k];
            float4 p = q4[k];
            acc += w.x * p.x + w.y * p.y + w.z * p.z + w.w * p.w;
        }
        q[tid] = acc;
    }
    __syncthreads();
    if (tid == 0) {
        float W0 = q[0], W1 = q[1], W2 = q[2];
        float U0 = q[3], U1 = q[4], U2 = q[5];
        float G0 = q[6], G1 = q[7], G2 = q[8];
        float B  = q[9];
        U0 *= 1.0f / (1.0f + expf(-G0));
        U1 *= 1.0f / (1.0f + expf(-G1));
        U2 *= 1.0f / (1.0f + expf(-G2));
        float wu = W0 * U0 + W1 * U1 + W2 * U2;   // from UNSCALED W,U
        const float c = 2.8853900817779268f;
        const float s = 1.0f / (float)WIDTH;
        par[tb]         = make_float4(W0 * c, W1 * c, W2 * c, B * c);
        par[WIDTH + tb] = make_float4(U0 * s, U1 * s, U2 * s, -wu * s);
    }
}

// ---------------- kernel 2: batch loop, 2 elements/thread ----------------
// 977 blocks -> ~3.8 waves/SIMD; VALU/trans/LDS pipes near-balanced
// (~14 pk-VALU + 3 trans + 2 ds_read_b128 per pair per j).
__global__ __launch_bounds__(256) void cnf_main(
    const float* __restrict__ z,
    const float4* __restrict__ par,
    float* __restrict__ out)
{
    __shared__ float4 stab[2 * WIDTH];   // [0..63]=pA, [64..127]=pB

    const int tid = threadIdx.x;
    if (tid < 2 * WIDTH) stab[tid] = par[tid];
    __syncthreads();

    const int gid = blockIdx.x * blockDim.x + tid;
    if (gid >= NPAIR) return;

    // elements e0 = 2*gid, e1 = 2*gid+1; z row-major [BATCH][3]
    const f2* zp = (const f2*)z + (size_t)gid * 3;   // 24B/thread, 8B aligned
    f2 v0 = zp[0], v1 = zp[1], v2 = zp[2];
    f2 z0 = {v0.x, v1.y};   // {z[e0][0], z[e1][0]}
    f2 z1 = {v0.y, v2.x};   // {z[e0][1], z[e1][1]}
    f2 z2 = {v1.x, v2.y};   // {z[e0][2], z[e1][2]}

    f2 dz0 = sp(0.f), dz1 = sp(0.f), dz2 = sp(0.f), tr = sp(0.f);

    const float4* sA = stab;
    const float4* sB = stab + WIDTH;

    #pragma unroll 8
    for (int j = 0; j < WIDTH; ++j) {
        float4 a = sA[j];   // scaled W0,W1,W2,B (LDS broadcast, conflict-free)
        float4 b = sB[j];   // scaled U0,U1,U2,-wu

        // x' = c*(z.W + B), clamped at 30 (exact: h(30') == 1.0f in fp32;
        // also keeps the 2-way Montgomery product finite)
        f2 x = vfma(z0, sp(a.x), vfma(z1, sp(a.y), vfma(z2, sp(a.z), sp(a.w))));
        x = __builtin_elementwise_min(x, sp(30.0f));

        f2 d;                                  // d_e = 1 + 2^(x'_e)
        d.x = __builtin_amdgcn_exp2f(x.x);
        d.y = __builtin_amdgcn_exp2f(x.y);
        d = d + sp(1.0f);

        // Montgomery batch inversion over the pair: 1 rcp for 2 elements
        float R = __builtin_amdgcn_rcpf(d.x * d.y);
        f2 inv; inv.x = R * d.y; inv.y = R * d.x;

        f2 h  = vfma(sp(-2.0f), inv, sp(1.0f));  // tanh
        f2 g1 = vfma(-h, h, sp(1.0f));           // 1 - h^2

        dz0 = vfma(h,  sp(b.x), dz0);
        dz1 = vfma(h,  sp(b.y), dz1);
        dz2 = vfma(h,  sp(b.z), dz2);
        tr  = vfma(g1, sp(b.w), tr);
    }

    // scale (1/64) and trace negation pre-folded into pB
    f2* o = (f2*)out + (size_t)gid * 3;
    f2 w0 = {dz0.x, dz1.x};
    f2 w1 = {dz2.x, dz0.y};
    f2 w2 = {dz1.y, dz2.y};
    o[0] = w0; o[1] = w1; o[2] = w2;

    ((f2*)(out + 3 * BATCH))[gid] = tr;          // dlogp pair, coalesced
}

extern "C" void kernel_launch(void* const* d_in, const int* in_sizes, int n_in,
                              void* d_out, int out_size, void* d_ws, size_t ws_size,
                              hipStream_t stream) {
    const float* t     = (const float*)d_in[0];
    const float* z     = (const float*)d_in[1];
    // d_in[2] = logp_z : unused by the reference computation
    const float* fc1_w = (const float*)d_in[3];
    const float* fc1_b = (const float*)d_in[4];
    const float* fc2_w = (const float*)d_in[5];
    const float* fc2_b = (const float*)d_in[6];
    const float* fc3_w = (const float*)d_in[7];
    const float* fc3_b = (const float*)d_in[8];
    float* out = (float*)d_out;

    float4* par = (float4*)d_ws;   // 2 KB param table, written each iteration

    hyper_kernel<<<64, 64, 0, stream>>>(
        t, fc1_w, fc1_b, fc2_w, fc2_b, fc3_w, fc3_b, par);

    const int threads = 256;
    const int blocks  = (NPAIR + threads - 1) / threads;  // 977
    cnf_main<<<blocks, threads, 0, stream>>>(z, par, out);
}

// Round 3
// 89.527 us; speedup vs baseline: 1.0620x; 1.0349x over previous
//
#include <hip/hip_runtime.h>
#include <math.h>

#define D      3
#define HID    64
#define WIDTH  64
#define BATCH  500000
#define BLOCKP (D * WIDTH)          // 192
#define NPAR   (3 * BLOCKP + WIDTH) // 640
#define NPAIR  (BATCH / 2)          // 250000 pairs of 2 elements

typedef float f2 __attribute__((ext_vector_type(2)));

__device__ __forceinline__ f2 sp(float s) { f2 r; r.x = s; r.y = s; return r; }
__device__ __forceinline__ f2 vfma(f2 a, f2 b, f2 c) {
    return __builtin_elementwise_fma(a, b, c);
}

// ---------------- kernel 1: hypernet (64 blocks x 64 threads) ----------------
// Block b computes ONLY the 10 fc3 rows needed for folded output b:
//   rows 3b..3b+2 (W), BLOCKP+3b.. (U), 2*BLOCKP+3b.. (G), 3*BLOCKP+b (B).
// p1/p2 recomputed redundantly per block (negligible); fc3_w traffic is
// 2.5 KB/block, zero redundancy, spread over 64 CUs.
// Writes par[0..63] = {W0*c, W1*c, W2*c, B*c}, par[64..127] = {U0/64, U1/64,
// U2/64, -wu/64}  (c = 2*log2(e), tanh(x) = 1 - 2/(1 + 2^(c*x))).
__global__ __launch_bounds__(64) void hyper_kernel(
    const float* __restrict__ t,
    const float* __restrict__ fc1_w, const float* __restrict__ fc1_b,
    const float* __restrict__ fc2_w, const float* __restrict__ fc2_b,
    const float* __restrict__ fc3_w, const float* __restrict__ fc3_b,
    float4* __restrict__ par)
{
    __shared__ float p1[HID];
    __shared__ float p2[HID];
    __shared__ float q[16];          // 10 used

    const int tid = threadIdx.x;
    const int tb  = blockIdx.x;      // fold output index 0..63

    p1[tid] = tanhf(t[0] * fc1_w[tid] + fc1_b[tid]);
    __syncthreads();
    {
        const float* wrow = fc2_w + tid * HID;
        float a0 = 0.f, a1 = 0.f, a2 = 0.f, a3 = 0.f;
        #pragma unroll
        for (int k = 0; k < HID; k += 4) {
            a0 = fmaf(wrow[k + 0], p1[k + 0], a0);
            a1 = fmaf(wrow[k + 1], p1[k + 1], a1);
            a2 = fmaf(wrow[k + 2], p1[k + 2], a2);
            a3 = fmaf(wrow[k + 3], p1[k + 3], a3);
        }
        p2[tid] = tanhf(((a0 + a1) + (a2 + a3)) + fc2_b[tid]);
    }
    __syncthreads();
    if (tid < 10) {
        // tid 0..2 -> W rows, 3..5 -> U rows, 6..8 -> G rows, 9 -> B row
        const int row = (tid < 9) ? ((tid / 3) * BLOCKP + 3 * tb + (tid % 3))
                                  : (3 * BLOCKP + tb);
        const float4* w4 = (const float4*)(fc3_w + (size_t)row * HID);
        const float4* q4 = (const float4*)p2;
        float acc = fc3_b[row];
        #pragma unroll
        for (int k = 0; k < HID / 4; ++k) {
            float4 w = w4[k];
            float4 p = q4[k];
            acc += w.x * p.x + w.y * p.y + w.z * p.z + w.w * p.w;
        }
        q[tid] = acc;
    }
    __syncthreads();
    if (tid == 0) {
        float W0 = q[0], W1 = q[1], W2 = q[2];
        float U0 = q[3], U1 = q[4], U2 = q[5];
        float G0 = q[6], G1 = q[7], G2 = q[8];
        float B  = q[9];
        U0 *= 1.0f / (1.0f + expf(-G0));
        U1 *= 1.0f / (1.0f + expf(-G1));
        U2 *= 1.0f / (1.0f + expf(-G2));
        float wu = W0 * U0 + W1 * U1 + W2 * U2;   // from UNSCALED W,U
        const float c = 2.8853900817779268f;
        const float s = 1.0f / (float)WIDTH;
        par[tb]         = make_float4(W0 * c, W1 * c, W2 * c, B * c);
        par[WIDTH + tb] = make_float4(U0 * s, U1 * s, U2 * s, -wu * s);
    }
}

// ---------------- kernel 2: batch loop, 2 elements/thread ----------------
// Param table read DIRECTLY from global with loop-uniform addresses ->
// compiler emits s_load_dwordx4 into SGPRs (scalar cache, 2 KB resident).
// No LDS staging, no __syncthreads, no ds_read in the inner loop: the
// VALU ops take the table operand from an SGPR source.
__global__ __launch_bounds__(256) void cnf_main(
    const float* __restrict__ z,
    const float4* __restrict__ par,
    float* __restrict__ out)
{
    const int tid = threadIdx.x;
    const int gid = blockIdx.x * blockDim.x + tid;
    if (gid >= NPAIR) return;

    // elements e0 = 2*gid, e1 = 2*gid+1; z row-major [BATCH][3]
    const f2* zp = (const f2*)z + (size_t)gid * 3;   // 24B/thread, 8B aligned
    f2 v0 = zp[0], v1 = zp[1], v2 = zp[2];
    f2 z0 = {v0.x, v1.y};   // {z[e0][0], z[e1][0]}
    f2 z1 = {v0.y, v2.x};   // {z[e0][1], z[e1][1]}
    f2 z2 = {v1.x, v2.y};   // {z[e0][2], z[e1][2]}

    f2 dz0 = sp(0.f), dz1 = sp(0.f), dz2 = sp(0.f), tr = sp(0.f);

    const float4* __restrict__ sA = par;
    const float4* __restrict__ sB = par + WIDTH;

    #pragma unroll 8
    for (int j = 0; j < WIDTH; ++j) {
        float4 a = sA[j];   // uniform -> s_load_dwordx4 {W0c,W1c,W2c,Bc}
        float4 b = sB[j];   // uniform -> s_load_dwordx4 {U0s,U1s,U2s,-wu*s}

        // x' = c*(z.W + B), clamped at 30 (exact: h(30') == 1.0f in fp32;
        // also keeps the 2-way Montgomery product finite)
        f2 x = vfma(z0, sp(a.x), vfma(z1, sp(a.y), vfma(z2, sp(a.z), sp(a.w))));
        x = __builtin_elementwise_min(x, sp(30.0f));

        f2 d;                                  // d_e = 1 + 2^(x'_e)
        d.x = __builtin_amdgcn_exp2f(x.x);
        d.y = __builtin_amdgcn_exp2f(x.y);
        d = d + sp(1.0f);

        // Montgomery batch inversion over the pair: 1 rcp for 2 elements
        float R = __builtin_amdgcn_rcpf(d.x * d.y);
        f2 inv; inv.x = R * d.y; inv.y = R * d.x;

        f2 h  = vfma(sp(-2.0f), inv, sp(1.0f));  // tanh
        f2 g1 = vfma(-h, h, sp(1.0f));           // 1 - h^2

        dz0 = vfma(h,  sp(b.x), dz0);
        dz1 = vfma(h,  sp(b.y), dz1);
        dz2 = vfma(h,  sp(b.z), dz2);
        tr  = vfma(g1, sp(b.w), tr);
    }

    // scale (1/64) and trace negation pre-folded into pB
    f2* o = (f2*)out + (size_t)gid * 3;
    f2 w0 = {dz0.x, dz1.x};
    f2 w1 = {dz2.x, dz0.y};
    f2 w2 = {dz1.y, dz2.y};
    o[0] = w0; o[1] = w1; o[2] = w2;

    ((f2*)(out + 3 * BATCH))[gid] = tr;          // dlogp pair, coalesced
}

extern "C" void kernel_launch(void* const* d_in, const int* in_sizes, int n_in,
                              void* d_out, int out_size, void* d_ws, size_t ws_size,
                              hipStream_t stream) {
    const float* t     = (const float*)d_in[0];
    const float* z     = (const float*)d_in[1];
    // d_in[2] = logp_z : unused by the reference computation
    const float* fc1_w = (const float*)d_in[3];
    const float* fc1_b = (const float*)d_in[4];
    const float* fc2_w = (const float*)d_in[5];
    const float* fc2_b = (const float*)d_in[6];
    const float* fc3_w = (const float*)d_in[7];
    const float* fc3_b = (const float*)d_in[8];
    float* out = (float*)d_out;

    float4* par = (float4*)d_ws;   // 2 KB param table, written each iteration

    hyper_kernel<<<64, 64, 0, stream>>>(
        t, fc1_w, fc1_b, fc2_w, fc2_b, fc3_w, fc3_b, par);

    const int threads = 256;
    const int blocks  = (NPAIR + threads - 1) / threads;  // 977
    cnf_main<<<blocks, threads, 0, stream>>>(z, par, out);
}